// Round 1
// baseline (946.671 us; speedup 1.0000x reference)
//
#include <hip/hip_runtime.h>
#include <hip/hip_bf16.h>

#define EMB 1024
#define NHEAD 16
#define HDIM 64
#define BB 4
#define TT 1024
#define SS 1024

typedef __attribute__((ext_vector_type(8))) short bf16x8;
typedef __attribute__((ext_vector_type(4))) float f32x4;

#define MFMA(a, b, c) __builtin_amdgcn_mfma_f32_16x16x32_bf16((a), (b), (c), 0, 0, 0)

// ws layout (byte offsets)
#define OFF_WQT_HI (0ull)
#define OFF_WQT_LO (2ull << 20)
#define OFF_WKT_HI (4ull << 20)
#define OFF_WKT_LO (6ull << 20)
#define OFF_WVT_HI (8ull << 20)
#define OFF_WOT_HI (10ull << 20)
#define OFF_QH (12ull << 20)
#define OFF_QL (20ull << 20)
#define OFF_KH (28ull << 20)
#define OFF_KL (36ull << 20)
#define OFF_V  (44ull << 20)
#define OFF_VT (52ull << 20)
#define OFF_H  (60ull << 20)

__device__ __forceinline__ float bf2f(short s) {
    union { unsigned u; float f; } v;
    v.u = ((unsigned)(unsigned short)s) << 16;
    return v.f;
}
__device__ __forceinline__ short f2bf(float f) {
    union { float f; unsigned u; } v;
    v.f = f;
    unsigned r = v.u + 0x7fffu + ((v.u >> 16) & 1u);  // RTNE (finite values)
    return (short)(r >> 16);
}

// ---------------------------------------------------------------------------
// Weight transform: W[k][n] f32 -> WT[n][k] bf16 hi (+lo for z<2).
// grid (16 n-tiles, 16 k-tiles, 4 weights), 256 threads
// ---------------------------------------------------------------------------
__global__ __launch_bounds__(256) void wtrans_kernel(
    const float* __restrict__ Wq, const float* __restrict__ Wk,
    const float* __restrict__ Wv, const float* __restrict__ Wo,
    char* __restrict__ ws) {
    __shared__ float tile[64][65];
    int z = blockIdx.z;
    const float* W = (z == 0) ? Wq : (z == 1) ? Wk : (z == 2) ? Wv : Wo;
    short* out_hi = (short*)(ws + ((z == 0) ? OFF_WQT_HI : (z == 1) ? OFF_WKT_HI
                                   : (z == 2) ? OFF_WVT_HI : OFF_WOT_HI));
    short* out_lo = (z == 0) ? (short*)(ws + OFF_WQT_LO)
                  : (z == 1) ? (short*)(ws + OFF_WKT_LO) : nullptr;
    int k0 = blockIdx.y * 64, n0 = blockIdx.x * 64;
    int tid = threadIdx.x;
    int kl = tid >> 2, nc = (tid & 3) * 16;
    const float4* src = (const float4*)(W + (size_t)(k0 + kl) * EMB + n0 + nc);
#pragma unroll
    for (int i = 0; i < 4; i++) {
        float4 v = src[i];
        tile[kl][nc + i * 4 + 0] = v.x;
        tile[kl][nc + i * 4 + 1] = v.y;
        tile[kl][nc + i * 4 + 2] = v.z;
        tile[kl][nc + i * 4 + 3] = v.w;
    }
    __syncthreads();
    int nl = tid >> 2, kc = (tid & 3) * 16;
    short hi[16], lo[16];
#pragma unroll
    for (int i = 0; i < 16; i++) {
        float f = tile[kc + i][nl];
        hi[i] = f2bf(f);
        lo[i] = f2bf(f - bf2f(hi[i]));
    }
    short* dst = out_hi + (size_t)(n0 + nl) * EMB + k0 + kc;
    *(bf16x8*)dst = *(bf16x8*)hi;
    *(bf16x8*)(dst + 8) = *(bf16x8*)(hi + 8);
    if (out_lo) {
        short* dstl = out_lo + (size_t)(n0 + nl) * EMB + k0 + kc;
        *(bf16x8*)dstl = *(bf16x8*)lo;
        *(bf16x8*)(dstl + 8) = *(bf16x8*)(lo + 8);
    }
}

// ---------------------------------------------------------------------------
// Projection GEMM: C[M=4096, N=1024] = A_f32 @ W  (W given as WT[n][k] bf16)
// MODE 0: split (3 MFMAs), writes hi/lo bf16 into [B,H,T,D]
// MODE 1: plain, writes bf16 into [B,H,S,D]
// grid (N/64=16, M/64=64), 256 threads (4 waves, 2x2 of 32x32)
// ---------------------------------------------------------------------------
template <int MODE>
__global__ __launch_bounds__(256) void proj_kernel(
    const float* __restrict__ A, const short* __restrict__ Bh,
    const short* __restrict__ Bl, short* __restrict__ Oh,
    short* __restrict__ Ol) {
    int tid = threadIdx.x;
    int w = tid >> 6, lane = tid & 63;
    int r = lane & 15, g = lane >> 4;
    int m0 = blockIdx.y * 64 + (w >> 1) * 32;
    int n0 = blockIdx.x * 64 + (w & 1) * 32;
    f32x4 acc[2][2] = {};
    for (int kk = 0; kk < EMB; kk += 32) {
        bf16x8 ah[2], al[2], bh[2], bl[2];
#pragma unroll
        for (int mi = 0; mi < 2; mi++) {
            const float* ap = A + (size_t)(m0 + mi * 16 + r) * EMB + kk + g * 8;
            float4 a0 = *(const float4*)ap;
            float4 a1 = *(const float4*)(ap + 4);
            float av[8] = {a0.x, a0.y, a0.z, a0.w, a1.x, a1.y, a1.z, a1.w};
            short h8[8], l8[8];
#pragma unroll
            for (int i = 0; i < 8; i++) {
                h8[i] = f2bf(av[i]);
                if (MODE == 0) l8[i] = f2bf(av[i] - bf2f(h8[i]));
            }
            ah[mi] = *(bf16x8*)h8;
            if (MODE == 0) al[mi] = *(bf16x8*)l8;
        }
#pragma unroll
        for (int ni = 0; ni < 2; ni++) {
            bh[ni] = *(const bf16x8*)(Bh + (size_t)(n0 + ni * 16 + r) * EMB + kk + g * 8);
            if (MODE == 0)
                bl[ni] = *(const bf16x8*)(Bl + (size_t)(n0 + ni * 16 + r) * EMB + kk + g * 8);
        }
#pragma unroll
        for (int mi = 0; mi < 2; mi++) {
#pragma unroll
            for (int ni = 0; ni < 2; ni++) {
                acc[mi][ni] = MFMA(ah[mi], bh[ni], acc[mi][ni]);
                if (MODE == 0) {
                    acc[mi][ni] = MFMA(ah[mi], bl[ni], acc[mi][ni]);
                    acc[mi][ni] = MFMA(al[mi], bh[ni], acc[mi][ni]);
                }
            }
        }
    }
#pragma unroll
    for (int mi = 0; mi < 2; mi++) {
#pragma unroll
        for (int ni = 0; ni < 2; ni++) {
#pragma unroll
            for (int j = 0; j < 4; j++) {
                int m = m0 + mi * 16 + g * 4 + j;
                int n = n0 + ni * 16 + r;
                int b = m >> 10, t = m & 1023;  // rows = b*1024 + t(or s)
                int h = n >> 6, d = n & 63;
                float v_ = acc[mi][ni][j];
                size_t idx = ((size_t)(b * NHEAD + h) * TT + t) * HDIM + d;
                short hi_ = f2bf(v_);
                Oh[idx] = hi_;
                if (MODE == 0) Ol[idx] = f2bf(v_ - bf2f(hi_));
            }
        }
    }
}

// ---------------------------------------------------------------------------
// V transpose: V[B,H,S,D] bf16 -> VT[B,H,D,S] bf16. grid (S/64=16, B*H=64)
// ---------------------------------------------------------------------------
__global__ __launch_bounds__(256) void vtrans_kernel(const short* __restrict__ V,
                                                     short* __restrict__ VT) {
    __shared__ short tile[64][72];
    int bh = blockIdx.y;
    int s0 = blockIdx.x * 64;
    int tid = threadIdx.x;
    int sl = tid >> 2, dc = (tid & 3) * 16;
    const short* src = V + ((size_t)bh * SS + s0 + sl) * HDIM + dc;
    *(bf16x8*)&tile[sl][dc] = *(const bf16x8*)src;
    *(bf16x8*)&tile[sl][dc + 8] = *(const bf16x8*)(src + 8);
    __syncthreads();
    int dl = tid >> 2, sc = (tid & 3) * 16;
    short v[16];
#pragma unroll
    for (int i = 0; i < 16; i++) v[i] = tile[sc + i][dl];
    short* dst = VT + ((size_t)bh * HDIM + dl) * SS + s0 + sc;
    *(bf16x8*)dst = *(bf16x8*)v;
    *(bf16x8*)(dst + 8) = *(bf16x8*)(v + 8);
}

// ---------------------------------------------------------------------------
// Attention scores + softmax + attn write.
// grid (T/16=64, B*H=64), 256 threads: 4 waves, each wave = 16 t-rows x 256 s.
// Split QK^T (hi/lo), f32 softmax, writes attn [B,H,T,S] f32.
// ---------------------------------------------------------------------------
__global__ __launch_bounds__(256) void attn_kernel(
    const short* __restrict__ Qh, const short* __restrict__ Ql,
    const short* __restrict__ Kh, const short* __restrict__ Kl,
    const float* __restrict__ tpm, const float* __restrict__ spm,
    const float* __restrict__ am, const int* __restrict__ iscz,
    float* __restrict__ attn) {
    __shared__ float smax[4][16];
    __shared__ float ssum[4][16];
    int bh = blockIdx.y;
    int b = bh >> 4;
    int t0 = blockIdx.x * 16;
    int tid = threadIdx.x;
    int w = tid >> 6, lane = tid & 63;
    int r = lane & 15, g = lane >> 4;
    int causal = *iscz;

    const short* qb = Qh + ((size_t)bh * TT + t0 + r) * HDIM + g * 8;
    const short* qlb = Ql + ((size_t)bh * TT + t0 + r) * HDIM + g * 8;
    bf16x8 qh0 = *(const bf16x8*)qb;
    bf16x8 qh1 = *(const bf16x8*)(qb + 32);
    bf16x8 ql0 = *(const bf16x8*)qlb;
    bf16x8 ql1 = *(const bf16x8*)(qlb + 32);

    int sbase = w * 256;
    f32x4 sc[16];
#pragma unroll
    for (int st = 0; st < 16; st++) {
        int s = sbase + st * 16 + r;
        const short* kb = Kh + ((size_t)bh * SS + s) * HDIM + g * 8;
        const short* klb = Kl + ((size_t)bh * SS + s) * HDIM + g * 8;
        bf16x8 kh0 = *(const bf16x8*)kb;
        bf16x8 kh1 = *(const bf16x8*)(kb + 32);
        bf16x8 kl0 = *(const bf16x8*)klb;
        bf16x8 kl1 = *(const bf16x8*)(klb + 32);
        f32x4 c = {};
        c = MFMA(qh0, kh0, c);
        c = MFMA(qh1, kh1, c);
        c = MFMA(qh0, kl0, c);
        c = MFMA(qh1, kl1, c);
        c = MFMA(ql0, kh0, c);
        c = MFMA(ql1, kh1, c);
        sc[st] = c;
    }

    float tp[4];
#pragma unroll
    for (int j = 0; j < 4; j++) tp[j] = tpm[b * TT + t0 + g * 4 + j];
    float mx[4] = {-1e30f, -1e30f, -1e30f, -1e30f};
#pragma unroll
    for (int st = 0; st < 16; st++) {
        int s = sbase + st * 16 + r;
        float sp = spm[b * SS + s];
#pragma unroll
        for (int j = 0; j < 4; j++) {
            int t = t0 + g * 4 + j;
            float m_ = tp[j] * sp * am[((size_t)b * TT + t) * SS + s];
            if (causal && s > t) m_ = 0.f;
            float v_ = sc[st][j] * 0.125f + m_;
            sc[st][j] = v_;
            mx[j] = fmaxf(mx[j], v_);
        }
    }
#pragma unroll
    for (int msk = 1; msk < 16; msk <<= 1) {
#pragma unroll
        for (int j = 0; j < 4; j++) mx[j] = fmaxf(mx[j], __shfl_xor(mx[j], msk));
    }
    if (r == 0) {
#pragma unroll
        for (int j = 0; j < 4; j++) smax[w][g * 4 + j] = mx[j];
    }
    __syncthreads();
#pragma unroll
    for (int j = 0; j < 4; j++) {
        float m_ = fmaxf(fmaxf(smax[0][g * 4 + j], smax[1][g * 4 + j]),
                         fmaxf(smax[2][g * 4 + j], smax[3][g * 4 + j]));
        mx[j] = m_;
    }
    float sum[4] = {0.f, 0.f, 0.f, 0.f};
#pragma unroll
    for (int st = 0; st < 16; st++) {
#pragma unroll
        for (int j = 0; j < 4; j++) {
            float e = __expf(sc[st][j] - mx[j]);
            sc[st][j] = e;
            sum[j] += e;
        }
    }
#pragma unroll
    for (int msk = 1; msk < 16; msk <<= 1) {
#pragma unroll
        for (int j = 0; j < 4; j++) sum[j] += __shfl_xor(sum[j], msk);
    }
    if (r == 0) {
#pragma unroll
        for (int j = 0; j < 4; j++) ssum[w][g * 4 + j] = sum[j];
    }
    __syncthreads();
    float rcp[4];
#pragma unroll
    for (int j = 0; j < 4; j++)
        rcp[j] = 1.f / (ssum[0][g * 4 + j] + ssum[1][g * 4 + j] +
                        ssum[2][g * 4 + j] + ssum[3][g * 4 + j]);
#pragma unroll
    for (int st = 0; st < 16; st++) {
#pragma unroll
        for (int j = 0; j < 4; j++) {
            int t = t0 + g * 4 + j;
            int s = sbase + st * 16 + r;
            attn[((size_t)bh * TT + t) * SS + s] = sc[st][j] * rcp[j];
        }
    }
}

// ---------------------------------------------------------------------------
// PV: O[b,h,t,d] = sum_s attn[b,h,t,s] * V[b,h,s,d], write H[(t*B+b)*E + h*D+d]
// grid (T/64=16, B*H=64), 256 threads: wave w does 16 t-rows, full d=64.
// ---------------------------------------------------------------------------
__global__ __launch_bounds__(256) void pv_kernel(const float* __restrict__ attn,
                                                 const short* __restrict__ VT,
                                                 short* __restrict__ H) {
    int bh = blockIdx.y;
    int b = bh >> 4, h = bh & 15;
    int tid = threadIdx.x;
    int w = tid >> 6, lane = tid & 63;
    int r = lane & 15, g = lane >> 4;
    int t0 = blockIdx.x * 64 + w * 16;
    f32x4 acc[4] = {};
    for (int s0 = 0; s0 < SS; s0 += 32) {
        const float* prow = attn + ((size_t)bh * TT + t0 + r) * SS + s0 + g * 8;
        float4 p0 = *(const float4*)prow;
        float4 p1 = *(const float4*)(prow + 4);
        float pv[8] = {p0.x, p0.y, p0.z, p0.w, p1.x, p1.y, p1.z, p1.w};
        short p8[8];
#pragma unroll
        for (int i = 0; i < 8; i++) p8[i] = f2bf(pv[i]);
        bf16x8 pa = *(bf16x8*)p8;
#pragma unroll
        for (int dt = 0; dt < 4; dt++) {
            bf16x8 vb = *(const bf16x8*)(VT + ((size_t)bh * HDIM + dt * 16 + r) * SS + s0 + g * 8);
            acc[dt] = MFMA(pa, vb, acc[dt]);
        }
    }
#pragma unroll
    for (int dt = 0; dt < 4; dt++) {
#pragma unroll
        for (int j = 0; j < 4; j++) {
            int t = t0 + g * 4 + j;
            int d = dt * 16 + r;
            H[((size_t)t * BB + b) * EMB + h * HDIM + d] = f2bf(acc[dt][j]);
        }
    }
}

// ---------------------------------------------------------------------------
// Output projection: out[m, n] = H[m,:] @ Wo[:,n] + bo[n], m = t*B+b (linear)
// grid (16, 64), 256 threads, 2x2 waves of 32x32.
// ---------------------------------------------------------------------------
__global__ __launch_bounds__(256) void outproj_kernel(
    const short* __restrict__ A, const short* __restrict__ Bt,
    const float* __restrict__ bo, float* __restrict__ out) {
    int tid = threadIdx.x;
    int w = tid >> 6, lane = tid & 63;
    int r = lane & 15, g = lane >> 4;
    int m0 = blockIdx.y * 64 + (w >> 1) * 32;
    int n0 = blockIdx.x * 64 + (w & 1) * 32;
    f32x4 acc[2][2] = {};
    for (int kk = 0; kk < EMB; kk += 32) {
        bf16x8 a[2], bb[2];
#pragma unroll
        for (int mi = 0; mi < 2; mi++)
            a[mi] = *(const bf16x8*)(A + (size_t)(m0 + mi * 16 + r) * EMB + kk + g * 8);
#pragma unroll
        for (int ni = 0; ni < 2; ni++)
            bb[ni] = *(const bf16x8*)(Bt + (size_t)(n0 + ni * 16 + r) * EMB + kk + g * 8);
#pragma unroll
        for (int mi = 0; mi < 2; mi++) {
#pragma unroll
            for (int ni = 0; ni < 2; ni++) acc[mi][ni] = MFMA(a[mi], bb[ni], acc[mi][ni]);
        }
    }
#pragma unroll
    for (int mi = 0; mi < 2; mi++) {
#pragma unroll
        for (int ni = 0; ni < 2; ni++) {
#pragma unroll
            for (int j = 0; j < 4; j++) {
                int m = m0 + mi * 16 + g * 4 + j;
                int n = n0 + ni * 16 + r;
                out[(size_t)m * EMB + n] = acc[mi][ni][j] + bo[n];
            }
        }
    }
}

extern "C" void kernel_launch(void* const* d_in, const int* in_sizes, int n_in,
                              void* d_out, int out_size, void* d_ws, size_t ws_size,
                              hipStream_t stream) {
    const float* src_emb = (const float*)d_in[0];
    const float* tgt_emb = (const float*)d_in[1];
    const float* spm = (const float*)d_in[2];
    const float* tpm = (const float*)d_in[3];
    const float* am = (const float*)d_in[4];
    const int* iscz = (const int*)d_in[5];
    const float* Wq = (const float*)d_in[6];
    const float* Wk = (const float*)d_in[7];
    const float* Wv = (const float*)d_in[8];
    const float* Wo = (const float*)d_in[9];
    const float* bo = (const float*)d_in[10];
    char* ws = (char*)d_ws;
    float* out = (float*)d_out;
    float* attn = out + (size_t)TT * BB * EMB;

    wtrans_kernel<<<dim3(16, 16, 4), 256, 0, stream>>>(Wq, Wk, Wv, Wo, ws);
    proj_kernel<0><<<dim3(16, 64), 256, 0, stream>>>(
        tgt_emb, (short*)(ws + OFF_WQT_HI), (short*)(ws + OFF_WQT_LO),
        (short*)(ws + OFF_QH), (short*)(ws + OFF_QL));
    proj_kernel<0><<<dim3(16, 64), 256, 0, stream>>>(
        src_emb, (short*)(ws + OFF_WKT_HI), (short*)(ws + OFF_WKT_LO),
        (short*)(ws + OFF_KH), (short*)(ws + OFF_KL));
    proj_kernel<1><<<dim3(16, 64), 256, 0, stream>>>(
        src_emb, (short*)(ws + OFF_WVT_HI), nullptr, (short*)(ws + OFF_V), nullptr);
    vtrans_kernel<<<dim3(16, 64), 256, 0, stream>>>((short*)(ws + OFF_V),
                                                    (short*)(ws + OFF_VT));
    attn_kernel<<<dim3(64, 64), 256, 0, stream>>>(
        (short*)(ws + OFF_QH), (short*)(ws + OFF_QL), (short*)(ws + OFF_KH),
        (short*)(ws + OFF_KL), tpm, spm, am, iscz, attn);
    pv_kernel<<<dim3(16, 64), 256, 0, stream>>>(attn, (short*)(ws + OFF_VT),
                                                (short*)(ws + OFF_H));
    outproj_kernel<<<dim3(16, 64), 256, 0, stream>>>(
        (short*)(ws + OFF_H), (short*)(ws + OFF_WOT_HI), bo, out);
}

// Round 2
// 686.161 us; speedup vs baseline: 1.3797x; 1.3797x over previous
//
#include <hip/hip_runtime.h>
#include <hip/hip_bf16.h>

#define EMB 1024
#define NHEAD 16
#define HDIM 64
#define BB 4
#define TT 1024
#define SS 1024

typedef __attribute__((ext_vector_type(8))) short bf16x8;
typedef __attribute__((ext_vector_type(4))) float f32x4;

#define MFMA(a, b, c) __builtin_amdgcn_mfma_f32_16x16x32_bf16((a), (b), (c), 0, 0, 0)

// ws layout (byte offsets)
#define OFF_WQT_HI (0ull)
#define OFF_WQT_LO (2ull << 20)
#define OFF_WKT_HI (4ull << 20)
#define OFF_WKT_LO (6ull << 20)
#define OFF_WVT_HI (8ull << 20)
#define OFF_WOT_HI (10ull << 20)
#define OFF_QH (12ull << 20)
#define OFF_QL (20ull << 20)
#define OFF_KH (28ull << 20)
#define OFF_KL (36ull << 20)
#define OFF_VT (44ull << 20)
#define OFF_H  (52ull << 20)

__device__ __forceinline__ float bf2f(short s) {
    union { unsigned u; float f; } v;
    v.u = ((unsigned)(unsigned short)s) << 16;
    return v.f;
}
__device__ __forceinline__ short f2bf(float f) {
    union { float f; unsigned u; } v;
    v.f = f;
    unsigned r = v.u + 0x7fffu + ((v.u >> 16) & 1u);  // RTNE (finite values)
    return (short)(r >> 16);
}

__device__ __forceinline__ void gl_lds16(const short* g, short* l) {
    __builtin_amdgcn_global_load_lds(
        (const __attribute__((address_space(1))) unsigned int*)(g),
        (__attribute__((address_space(3))) unsigned int*)(l), 16, 0, 0);
}

// ---------------------------------------------------------------------------
// Elementwise f32 -> bf16 hi/lo split. 8 elems/thread.
// ---------------------------------------------------------------------------
__global__ __launch_bounds__(256) void conv_kernel(const float* __restrict__ in,
                                                   short* __restrict__ hi,
                                                   short* __restrict__ lo) {
    size_t i = ((size_t)blockIdx.x * 256 + threadIdx.x) * 8;
    float4 a = *(const float4*)(in + i);
    float4 b = *(const float4*)(in + i + 4);
    float v[8] = {a.x, a.y, a.z, a.w, b.x, b.y, b.z, b.w};
    short h8[8], l8[8];
#pragma unroll
    for (int k = 0; k < 8; k++) {
        h8[k] = f2bf(v[k]);
        l8[k] = f2bf(v[k] - bf2f(h8[k]));
    }
    *(bf16x8*)(hi + i) = *(bf16x8*)h8;
    *(bf16x8*)(lo + i) = *(bf16x8*)l8;
}

// ---------------------------------------------------------------------------
// Weight transform: W[k][n] f32 -> WT[n][k] bf16 hi (+lo for z<2).
// ---------------------------------------------------------------------------
__global__ __launch_bounds__(256) void wtrans_kernel(
    const float* __restrict__ Wq, const float* __restrict__ Wk,
    const float* __restrict__ Wv, const float* __restrict__ Wo,
    char* __restrict__ ws) {
    __shared__ float tile[64][65];
    int z = blockIdx.z;
    const float* W = (z == 0) ? Wq : (z == 1) ? Wk : (z == 2) ? Wv : Wo;
    short* out_hi = (short*)(ws + ((z == 0) ? OFF_WQT_HI : (z == 1) ? OFF_WKT_HI
                                   : (z == 2) ? OFF_WVT_HI : OFF_WOT_HI));
    short* out_lo = (z == 0) ? (short*)(ws + OFF_WQT_LO)
                  : (z == 1) ? (short*)(ws + OFF_WKT_LO) : nullptr;
    int k0 = blockIdx.y * 64, n0 = blockIdx.x * 64;
    int tid = threadIdx.x;
    int kl = tid >> 2, nc = (tid & 3) * 16;
    const float4* src = (const float4*)(W + (size_t)(k0 + kl) * EMB + n0 + nc);
#pragma unroll
    for (int i = 0; i < 4; i++) {
        float4 v = src[i];
        tile[kl][nc + i * 4 + 0] = v.x;
        tile[kl][nc + i * 4 + 1] = v.y;
        tile[kl][nc + i * 4 + 2] = v.z;
        tile[kl][nc + i * 4 + 3] = v.w;
    }
    __syncthreads();
    int nl = tid >> 2, kc = (tid & 3) * 16;
    short hi[16], lo[16];
#pragma unroll
    for (int i = 0; i < 16; i++) {
        float f = tile[kc + i][nl];
        hi[i] = f2bf(f);
        lo[i] = f2bf(f - bf2f(hi[i]));
    }
    short* dst = out_hi + (size_t)(n0 + nl) * EMB + k0 + kc;
    *(bf16x8*)dst = *(bf16x8*)hi;
    *(bf16x8*)(dst + 8) = *(bf16x8*)(hi + 8);
    if (out_lo) {
        short* dstl = out_lo + (size_t)(n0 + nl) * EMB + k0 + kc;
        *(bf16x8*)dstl = *(bf16x8*)lo;
        *(bf16x8*)(dstl + 8) = *(bf16x8*)(lo + 8);
    }
}

// ---------------------------------------------------------------------------
// LDS-staged GEMM: C[M=4096][N=1024] = A @ B^T, A[m][k], B given as BT[n][k],
// all bf16 (hi/lo split optional). BM=128, BN=64, BK=32, 256 thr (4 waves 2x2).
// EPI 0: Q/K -> [B,H,T,D] hi/lo bf16, *scale.  EPI 1: VT [B,H,D,S] bf16.
// EPI 2: out f32 [m][n] + bias.
// ---------------------------------------------------------------------------
template <int SPLIT, int EPI>
__global__ __launch_bounds__(256) void gemm_kernel(
    const short* __restrict__ Ah_g, const short* __restrict__ Al_g,
    const short* __restrict__ Bh_g, const short* __restrict__ Bl_g,
    void* __restrict__ out1, void* __restrict__ out2,
    const float* __restrict__ bias, float scale) {
    constexpr int AhO = 0;
    constexpr int AlO = 4096;
    constexpr int BhO = SPLIT ? 8192 : 4096;
    constexpr int BlO = 10240;
    __shared__ __align__(16) short lds[SPLIT ? 12288 : 6144];
    int tid = threadIdx.x, w = tid >> 6, lane = tid & 63;
    int r = lane & 15, g = lane >> 4;
    int wr = w >> 1, wc = w & 1;
    int m0 = blockIdx.y * 128, n0 = blockIdx.x * 64;

    int srow = tid >> 2, scol = (tid & 3) * 8;
    const short* agp0 = Ah_g + (size_t)(m0 + srow) * EMB + scol;
    const short* agp1 = agp0 + 64 * EMB;
    const short* bgp = Bh_g + (size_t)(n0 + srow) * EMB + scol;
    const short* algp0 = SPLIT ? (Al_g + (size_t)(m0 + srow) * EMB + scol) : nullptr;
    const short* algp1 = SPLIT ? (algp0 + 64 * EMB) : nullptr;
    const short* blgp = SPLIT ? (Bl_g + (size_t)(n0 + srow) * EMB + scol) : nullptr;
    short* ldsA0 = lds + AhO + w * 512;
    short* ldsA1 = lds + AhO + 2048 + w * 512;
    short* ldsB = lds + BhO + w * 512;
    short* ldsAl0 = lds + AlO + w * 512;
    short* ldsAl1 = lds + AlO + 2048 + w * 512;
    short* ldsBl = lds + BlO + w * 512;

    f32x4 acc[4][2] = {};
    for (int kk = 0; kk < EMB; kk += 32) {
        __syncthreads();
        gl_lds16(agp0 + kk, ldsA0);
        gl_lds16(agp1 + kk, ldsA1);
        gl_lds16(bgp + kk, ldsB);
        if (SPLIT) {
            gl_lds16(algp0 + kk, ldsAl0);
            gl_lds16(algp1 + kk, ldsAl1);
            gl_lds16(blgp + kk, ldsBl);
        }
        __syncthreads();
        bf16x8 ah[4], al[4], bh2[2], bl2[2];
#pragma unroll
        for (int mi = 0; mi < 4; mi++) {
            int row = wr * 64 + mi * 16 + r;
            ah[mi] = *(const bf16x8*)(lds + AhO + row * 32 + g * 8);
            if (SPLIT) al[mi] = *(const bf16x8*)(lds + AlO + row * 32 + g * 8);
        }
#pragma unroll
        for (int ni = 0; ni < 2; ni++) {
            int row = wc * 32 + ni * 16 + r;
            bh2[ni] = *(const bf16x8*)(lds + BhO + row * 32 + g * 8);
            if (SPLIT) bl2[ni] = *(const bf16x8*)(lds + BlO + row * 32 + g * 8);
        }
#pragma unroll
        for (int mi = 0; mi < 4; mi++) {
#pragma unroll
            for (int ni = 0; ni < 2; ni++) {
                acc[mi][ni] = MFMA(ah[mi], bh2[ni], acc[mi][ni]);
                if (SPLIT) {
                    acc[mi][ni] = MFMA(ah[mi], bl2[ni], acc[mi][ni]);
                    acc[mi][ni] = MFMA(al[mi], bh2[ni], acc[mi][ni]);
                }
            }
        }
    }

#pragma unroll
    for (int mi = 0; mi < 4; mi++) {
#pragma unroll
        for (int ni = 0; ni < 2; ni++) {
            int n = n0 + wc * 32 + ni * 16 + r;
            if (EPI == 1) {
                int mb = m0 + wr * 64 + mi * 16 + g * 4;
                int b = mb >> 10, s = mb & 1023;
                int h = n >> 6, d = n & 63;
                short p4[4];
#pragma unroll
                for (int j = 0; j < 4; j++) p4[j] = f2bf(acc[mi][ni][j]);
                unsigned u0 = (unsigned)(unsigned short)p4[0] |
                              ((unsigned)(unsigned short)p4[1] << 16);
                unsigned u1 = (unsigned)(unsigned short)p4[2] |
                              ((unsigned)(unsigned short)p4[3] << 16);
                unsigned long long uu = u0 | ((unsigned long long)u1 << 32);
                *(unsigned long long*)((short*)out1 +
                                       (((size_t)(b * NHEAD + h) * HDIM + d) * SS + s)) = uu;
            } else {
#pragma unroll
                for (int j = 0; j < 4; j++) {
                    int m = m0 + wr * 64 + mi * 16 + g * 4 + j;
                    float v = acc[mi][ni][j] * scale;
                    if (EPI == 0) {
                        int b = m >> 10, t = m & 1023;
                        int h = n >> 6, d = n & 63;
                        size_t idx = ((size_t)(b * NHEAD + h) * TT + t) * HDIM + d;
                        short hi_ = f2bf(v);
                        ((short*)out1)[idx] = hi_;
                        if (SPLIT) ((short*)out2)[idx] = f2bf(v - bf2f(hi_));
                    } else {
                        ((float*)out1)[(size_t)m * EMB + n] = v + bias[n];
                    }
                }
            }
        }
    }
}

// ---------------------------------------------------------------------------
// Fused attention: QK^T (swapped, split) + mask + softmax + attn write + PV.
// grid (T/16=64, B*H=64), 256 threads (4 waves), wave w owns s in [w*256,+256).
// Lane (r,g): sc[st][j] = P[s = w*256+st*16+g*4+j][t = t0+r].
// ---------------------------------------------------------------------------
__global__ __launch_bounds__(256) void attn_fused_kernel(
    const short* __restrict__ Qh, const short* __restrict__ Ql,
    const short* __restrict__ Kh, const short* __restrict__ Kl,
    const short* __restrict__ VT, const float* __restrict__ tpm,
    const float* __restrict__ spm, const float* __restrict__ am,
    const int* __restrict__ iscz, float* __restrict__ attn,
    short* __restrict__ H) {
    __shared__ __align__(16) short Plds[4 * 16 * 256];  // 32 KB; Ored aliases
    __shared__ float smax[4][16];
    __shared__ float ssum[4][16];
    float* Ored = (float*)Plds;  // 4 waves x 16t x 64d f32 = 16 KB
    int bh = blockIdx.y, b = bh >> 4, h = bh & 15;
    int t0 = blockIdx.x * 16;
    int tid = threadIdx.x, w = tid >> 6, lane = tid & 63;
    int r = lane & 15, g = lane >> 4;
    int causal = *iscz;
    int sbase = w * 256;
    int t = t0 + r;

    const short* qp = Qh + ((size_t)bh * TT + t) * HDIM + g * 8;
    const short* qlp = Ql + ((size_t)bh * TT + t) * HDIM + g * 8;
    bf16x8 qh0 = *(const bf16x8*)qp;
    bf16x8 qh1 = *(const bf16x8*)(qp + 32);
    bf16x8 ql0 = *(const bf16x8*)qlp;
    bf16x8 ql1 = *(const bf16x8*)(qlp + 32);

    float tp = tpm[b * TT + t];
    float mx = -1e30f;
    f32x4 sc[16];
#pragma unroll
    for (int st = 0; st < 16; st++) {
        const short* kp = Kh + ((size_t)bh * SS + sbase + st * 16 + r) * HDIM + g * 8;
        const short* klp = Kl + ((size_t)bh * SS + sbase + st * 16 + r) * HDIM + g * 8;
        bf16x8 kh0 = *(const bf16x8*)kp;
        bf16x8 kh1 = *(const bf16x8*)(kp + 32);
        bf16x8 kl0 = *(const bf16x8*)klp;
        bf16x8 kl1 = *(const bf16x8*)(klp + 32);
        f32x4 c = {};
        c = MFMA(kh0, qh0, c);
        c = MFMA(kh1, qh1, c);
        c = MFMA(kh0, ql0, c);
        c = MFMA(kh1, ql1, c);
        c = MFMA(kl0, qh0, c);
        c = MFMA(kl1, qh1, c);
        int s0 = sbase + st * 16 + g * 4;
        float4 sp = *(const float4*)(spm + b * SS + s0);
        float4 amv = *(const float4*)(am + ((size_t)b * TT + t) * SS + s0);
        float spv[4] = {sp.x, sp.y, sp.z, sp.w};
        float amvv[4] = {amv.x, amv.y, amv.z, amv.w};
#pragma unroll
        for (int j = 0; j < 4; j++) {
            float m_ = tp * spv[j] * amvv[j];
            if (causal && (s0 + j) > t) m_ = 0.f;
            float v = c[j] + m_;
            c[j] = v;
            mx = fmaxf(mx, v);
        }
        sc[st] = c;
    }
    mx = fmaxf(mx, __shfl_xor(mx, 16));
    mx = fmaxf(mx, __shfl_xor(mx, 32));
    if (lane < 16) smax[w][lane] = mx;
    __syncthreads();
    float M = fmaxf(fmaxf(smax[0][r], smax[1][r]), fmaxf(smax[2][r], smax[3][r]));
    float sum = 0.f;
#pragma unroll
    for (int st = 0; st < 16; st++) {
#pragma unroll
        for (int j = 0; j < 4; j++) {
            float e = __expf(sc[st][j] - M);
            sc[st][j] = e;
            sum += e;
        }
    }
    sum += __shfl_xor(sum, 16);
    sum += __shfl_xor(sum, 32);
    if (lane < 16) ssum[w][lane] = sum;
    __syncthreads();
    float rcp = 1.f / (ssum[0][r] + ssum[1][r] + ssum[2][r] + ssum[3][r]);

    // normalize -> write attn (float4) + write P tile to LDS (swizzled b64)
    char* pbase = (char*)Plds + w * 8192 + r * 512;
    int swz = (r & 7) << 4;
#pragma unroll
    for (int st = 0; st < 16; st++) {
        float4 p;
        p.x = sc[st][0] * rcp;
        p.y = sc[st][1] * rcp;
        p.z = sc[st][2] * rcp;
        p.w = sc[st][3] * rcp;
        int s0 = sbase + st * 16 + g * 4;
        *(float4*)(attn + ((size_t)bh * TT + t) * SS + s0) = p;
        short p4[4] = {f2bf(p.x), f2bf(p.y), f2bf(p.z), f2bf(p.w)};
        unsigned u0 = (unsigned)(unsigned short)p4[0] |
                      ((unsigned)(unsigned short)p4[1] << 16);
        unsigned u1 = (unsigned)(unsigned short)p4[2] |
                      ((unsigned)(unsigned short)p4[3] << 16);
        unsigned long long uu = u0 | ((unsigned long long)u1 << 32);
        *(unsigned long long*)(pbase + (((st * 32 + g * 8)) ^ swz)) = uu;
    }

    // PV: O[t][d] += P[t][s] * V[s][d] over this wave's s-chunk.
    f32x4 oacc[4] = {};
#pragma unroll
    for (int step = 0; step < 8; step++) {
        bf16x8 pfrag = *(const bf16x8*)(pbase + ((step * 64 + g * 16) ^ swz));
#pragma unroll
        for (int dt = 0; dt < 4; dt++) {
            bf16x8 vfrag = *(const bf16x8*)(VT +
                ((size_t)(bh * HDIM + dt * 16 + r)) * SS + sbase + step * 32 + g * 8);
            oacc[dt] = MFMA(pfrag, vfrag, oacc[dt]);
        }
    }
    __syncthreads();  // all P reads done before Ored overwrites Plds
#pragma unroll
    for (int dt = 0; dt < 4; dt++) {
#pragma unroll
        for (int j = 0; j < 4; j++) {
            Ored[w * 1024 + (g * 4 + j) * 64 + dt * 16 + r] = oacc[dt][j];
        }
    }
    __syncthreads();
    // reduce 4 waves, write H[(t*B+b)*E + h*64 + d]
    int tl = tid >> 4, dblk = (tid & 15) * 4;
    f32x4 o = *(f32x4*)(Ored + 0 * 1024 + tl * 64 + dblk);
    f32x4 o1 = *(f32x4*)(Ored + 1 * 1024 + tl * 64 + dblk);
    f32x4 o2 = *(f32x4*)(Ored + 2 * 1024 + tl * 64 + dblk);
    f32x4 o3 = *(f32x4*)(Ored + 3 * 1024 + tl * 64 + dblk);
    o = o + o1 + o2 + o3;
    short h4[4] = {f2bf(o[0]), f2bf(o[1]), f2bf(o[2]), f2bf(o[3])};
    unsigned u0 = (unsigned)(unsigned short)h4[0] |
                  ((unsigned)(unsigned short)h4[1] << 16);
    unsigned u1 = (unsigned)(unsigned short)h4[2] |
                  ((unsigned)(unsigned short)h4[3] << 16);
    unsigned long long uu = u0 | ((unsigned long long)u1 << 32);
    *(unsigned long long*)(H + ((size_t)(t0 + tl) * BB + b) * EMB + h * HDIM + dblk) = uu;
}

extern "C" void kernel_launch(void* const* d_in, const int* in_sizes, int n_in,
                              void* d_out, int out_size, void* d_ws, size_t ws_size,
                              hipStream_t stream) {
    const float* src_emb = (const float*)d_in[0];
    const float* tgt_emb = (const float*)d_in[1];
    const float* spm = (const float*)d_in[2];
    const float* tpm = (const float*)d_in[3];
    const float* am = (const float*)d_in[4];
    const int* iscz = (const int*)d_in[5];
    const float* Wq = (const float*)d_in[6];
    const float* Wk = (const float*)d_in[7];
    const float* Wv = (const float*)d_in[8];
    const float* Wo = (const float*)d_in[9];
    const float* bo = (const float*)d_in[10];
    char* ws = (char*)d_ws;
    float* out = (float*)d_out;
    float* attn = out + (size_t)TT * BB * EMB;

    // activation hi/lo scratch lives in the attn region of d_out (written last)
    const size_t NE = (size_t)BB * TT * EMB;  // 4M elems
    short* Th = (short*)attn;
    short* Tl = Th + NE;
    short* Sh = Tl + NE;
    short* Sl = Sh + NE;

    conv_kernel<<<dim3(NE / 2048), 256, 0, stream>>>(tgt_emb, Th, Tl);
    conv_kernel<<<dim3(NE / 2048), 256, 0, stream>>>(src_emb, Sh, Sl);
    wtrans_kernel<<<dim3(16, 16, 4), 256, 0, stream>>>(Wq, Wk, Wv, Wo, ws);

    // Q = tgt @ Wq * 0.125 (split), K = src @ Wk (split), V^T = (src @ Wv)^T
    gemm_kernel<1, 0><<<dim3(16, 32), 256, 0, stream>>>(
        Th, Tl, (short*)(ws + OFF_WQT_HI), (short*)(ws + OFF_WQT_LO),
        ws + OFF_QH, ws + OFF_QL, nullptr, 0.125f);
    gemm_kernel<1, 0><<<dim3(16, 32), 256, 0, stream>>>(
        Sh, Sl, (short*)(ws + OFF_WKT_HI), (short*)(ws + OFF_WKT_LO),
        ws + OFF_KH, ws + OFF_KL, nullptr, 1.0f);
    gemm_kernel<0, 1><<<dim3(16, 32), 256, 0, stream>>>(
        Sh, nullptr, (short*)(ws + OFF_WVT_HI), nullptr,
        ws + OFF_VT, nullptr, nullptr, 1.0f);

    attn_fused_kernel<<<dim3(64, 64), 256, 0, stream>>>(
        (short*)(ws + OFF_QH), (short*)(ws + OFF_QL), (short*)(ws + OFF_KH),
        (short*)(ws + OFF_KL), (short*)(ws + OFF_VT), tpm, spm, am, iscz, attn,
        (short*)(ws + OFF_H));

    gemm_kernel<0, 2><<<dim3(16, 32), 256, 0, stream>>>(
        (short*)(ws + OFF_H), nullptr, (short*)(ws + OFF_WOT_HI), nullptr,
        out, nullptr, bo, 1.0f);
}